// Round 2
// baseline (193.572 us; speedup 1.0000x reference)
//
#include <hip/hip_runtime.h>
#include <math.h>

#define NTOK (16 * 4096)   // 65536 tokens
#define DIM  64
#define KC   512
#define TPB  64            // tokens per block

// ---------------------------------------------------------------------------
// Main kernel: block = 64 tokens, 256 threads (4 waves).
// Wave w handles codes [w*128, (w+1)*128) for all 64 tokens (lane = token).
// Codebook addresses are wave-uniform -> scalar loads; z lives in VGPRs.
// ---------------------------------------------------------------------------
__global__ __launch_bounds__(256, 4)
void vq_main(const float* __restrict__ z_e, const float* __restrict__ cb,
             float* __restrict__ z_q, float* __restrict__ qzx,
             float* __restrict__ e_k, int* __restrict__ counts)
{
    __shared__ float zs[TPB][DIM + 1];   // +1 pad: conflict-free row reads
    __shared__ float csq[KC];
    __shared__ float dred[4][TPB];
    __shared__ int   kred[4][TPB];
    __shared__ int   hist[KC];

    const int tid = threadIdx.x;
    const long tok0 = (long)blockIdx.x * TPB;

    hist[tid] = 0;
    hist[tid + 256] = 0;

    // ---- stage z (coalesced float4: 64 tok x 64 d = 1024 float4) ----
    {
        const float4* zg = (const float4*)(z_e + tok0 * DIM);
        #pragma unroll
        for (int it = 0; it < 4; ++it) {
            const int f4 = it * 256 + tid;
            const float4 v = zg[f4];
            const int row = f4 >> 4;
            const int c4  = (f4 & 15) << 2;
            zs[row][c4 + 0] = v.x; zs[row][c4 + 1] = v.y;
            zs[row][c4 + 2] = v.z; zs[row][c4 + 3] = v.w;
        }
    }

    // ---- codebook squared norms (2 codes / thread) ----
    #pragma unroll
    for (int it = 0; it < 2; ++it) {
        const int k = it * 256 + tid;
        const float4* cr = (const float4*)(cb + (size_t)k * DIM);
        float a0 = 0.f, a1 = 0.f, a2 = 0.f, a3 = 0.f;
        #pragma unroll
        for (int j = 0; j < 4; ++j) {
            const float4 v0 = cr[j], v1 = cr[4 + j], v2 = cr[8 + j], v3 = cr[12 + j];
            a0 += v0.x * v0.x + v0.y * v0.y + v0.z * v0.z + v0.w * v0.w;
            a1 += v1.x * v1.x + v1.y * v1.y + v1.z * v1.z + v1.w * v1.w;
            a2 += v2.x * v2.x + v2.y * v2.y + v2.z * v2.z + v2.w * v2.w;
            a3 += v3.x * v3.x + v3.y * v3.y + v3.z * v3.z + v3.w * v3.w;
        }
        csq[k] = (a0 + a1) + (a2 + a3);
    }
    __syncthreads();

    // ---- per-thread token into registers ----
    const int lane = tid & 63;
    float z[DIM];
    #pragma unroll
    for (int d = 0; d < DIM; ++d) z[d] = zs[lane][d];

    float s0 = 0.f, s1 = 0.f, s2 = 0.f, s3 = 0.f;
    #pragma unroll
    for (int d = 0; d < 16; ++d) {
        s0 += z[d]      * z[d];
        s1 += z[16 + d] * z[16 + d];
        s2 += z[32 + d] * z[32 + d];
        s3 += z[48 + d] * z[48 + d];
    }
    const float zsq = (s0 + s1) + (s2 + s3);

    // wave id as a proven-uniform scalar so codebook loads scalarize
    const int wvu = __builtin_amdgcn_readfirstlane(tid >> 6);
    const int kbase = wvu * 128;

    float dmin = INFINITY;
    int   kmin = 0;
    #pragma unroll 2
    for (int kk = 0; kk < 128; ++kk) {
        const int k = kbase + kk;
        const float4* c4p = (const float4*)(cb + (size_t)k * DIM);
        float a0 = 0.f, a1 = 0.f, a2 = 0.f, a3 = 0.f;
        #pragma unroll
        for (int j = 0; j < 4; ++j) {
            const float4 c0 = c4p[j], c1 = c4p[4 + j], c2 = c4p[8 + j], c3 = c4p[12 + j];
            a0 = fmaf(z[4 * j + 0], c0.x, a0);
            a0 = fmaf(z[4 * j + 1], c0.y, a0);
            a0 = fmaf(z[4 * j + 2], c0.z, a0);
            a0 = fmaf(z[4 * j + 3], c0.w, a0);
            a1 = fmaf(z[16 + 4 * j + 0], c1.x, a1);
            a1 = fmaf(z[16 + 4 * j + 1], c1.y, a1);
            a1 = fmaf(z[16 + 4 * j + 2], c1.z, a1);
            a1 = fmaf(z[16 + 4 * j + 3], c1.w, a1);
            a2 = fmaf(z[32 + 4 * j + 0], c2.x, a2);
            a2 = fmaf(z[32 + 4 * j + 1], c2.y, a2);
            a2 = fmaf(z[32 + 4 * j + 2], c2.z, a2);
            a2 = fmaf(z[32 + 4 * j + 3], c2.w, a2);
            a3 = fmaf(z[48 + 4 * j + 0], c3.x, a3);
            a3 = fmaf(z[48 + 4 * j + 1], c3.y, a3);
            a3 = fmaf(z[48 + 4 * j + 2], c3.z, a3);
            a3 = fmaf(z[48 + 4 * j + 3], c3.w, a3);
        }
        const float dot  = (a0 + a1) + (a2 + a3);
        const float dist = (zsq - 2.0f * dot) + csq[k];   // ref formula order
        if (dist < dmin) { dmin = dist; kmin = k; }        // first-min tiebreak
    }

    dred[tid >> 6][lane] = dmin;
    kred[tid >> 6][lane] = kmin;
    __syncthreads();

    // ---- cross-wave argmin reduce (wave 0), histogram, q_z_x ----
    if (tid < 64) {
        float dm = dred[0][tid];
        int   km = kred[0][tid];
        #pragma unroll
        for (int j = 1; j < 4; ++j) {
            const float dj = dred[j][tid];
            const int   kj = kred[j][tid];
            if (dj < dm) { dm = dj; km = kj; }   // equal -> keep lower k (earlier wave)
        }
        kred[0][tid] = km;
        atomicAdd(&hist[km], 1);
        qzx[tok0 + tid] = (float)km;             // index as float value
    }
    __syncthreads();

    atomicAdd(&counts[tid],       hist[tid]);
    atomicAdd(&counts[tid + 256], hist[tid + 256]);

    // ---- write e_k and z_q (coalesced float4) ----
    {
        float4* eo = (float4*)(e_k + tok0 * DIM);
        float4* zo = (float4*)(z_q + tok0 * DIM);
        #pragma unroll
        for (int it = 0; it < 4; ++it) {
            const int f4  = it * 256 + tid;
            const int row = f4 >> 4;
            const int c4  = (f4 & 15) << 2;
            const int km  = kred[0][row];
            const float4 cv = ((const float4*)(cb + (size_t)km * DIM))[f4 & 15];
            float4 zv;
            zv.x = zs[row][c4 + 0]; zv.y = zs[row][c4 + 1];
            zv.z = zs[row][c4 + 2]; zv.w = zs[row][c4 + 3];
            float4 q;  // z_q = z_e + (e_k - z_e), literally as in the reference
            q.x = zv.x + (cv.x - zv.x);
            q.y = zv.y + (cv.y - zv.y);
            q.z = zv.z + (cv.z - zv.z);
            q.w = zv.w + (cv.w - zv.w);
            eo[f4] = cv;
            zo[f4] = q;
        }
    }
}

// ---------------------------------------------------------------------------
// Perplexity from the global histogram (1 block, 512 threads)
// ---------------------------------------------------------------------------
__global__ void vq_perp(const int* __restrict__ counts, float* __restrict__ perp)
{
    const int tid = threadIdx.x;                  // 0..511
    const float p = (float)counts[tid] * (1.0f / 65536.0f);
    float s = p * logf(p + 1e-10f);
    #pragma unroll
    for (int off = 32; off > 0; off >>= 1) s += __shfl_down(s, off);
    __shared__ float red[8];
    if ((tid & 63) == 0) red[tid >> 6] = s;
    __syncthreads();
    if (tid == 0) {
        float tot = 0.f;
        #pragma unroll
        for (int j = 0; j < 8; ++j) tot += red[j];
        perp[0] = expf(-tot);
    }
}

extern "C" void kernel_launch(void* const* d_in, const int* in_sizes, int n_in,
                              void* d_out, int out_size, void* d_ws, size_t ws_size,
                              hipStream_t stream)
{
    const float* z_e = (const float*)d_in[0];
    const float* cb  = (const float*)d_in[1];

    float* out  = (float*)d_out;
    float* z_q  = out;                                   // 65536*64
    float* qzx  = out + (size_t)NTOK * DIM;              // 65536
    float* e_k  = qzx + NTOK;                            // 65536*64
    float* perp = e_k + (size_t)NTOK * DIM;              // 1

    int* counts = (int*)d_ws;                            // 512 ints, re-zeroed per call

    hipMemsetAsync(counts, 0, KC * sizeof(int), stream);
    vq_main<<<NTOK / TPB, 256, 0, stream>>>(z_e, cb, z_q, qzx, e_k, counts);
    vq_perp<<<1, KC, 0, stream>>>(counts, perp);
}